// Round 3
// baseline (43.735 us; speedup 1.0000x reference)
//
#include <hip/hip_runtime.h>
#include <hip/hip_bf16.h>

typedef __attribute__((ext_vector_type(8))) short short8_t;
typedef __attribute__((ext_vector_type(4))) float f32x4;

namespace {
constexpr int kB = 2048;
constexpr int kF = 64;
constexpr int kC = 10;
constexpr int kS = 5;
constexpr int kG = kC + kS;          // 15 groups total
constexpr int kH1 = 32;
constexpr int kH2 = 16;
constexpr float kWCat = 0.7f / kC;   // per-cat-group weight
constexpr float kWSub = 0.3f / kS;   // per-sub-group weight
constexpr int kThreads = 256;        // 4 waves
constexpr int kTPW = 2;              // 16-row MFMA tiles per wave
constexpr int kRowsPerBlock = 4 * kTPW * 16;   // 128
constexpr int kChunks = kB / kRowsPerBlock;    // 16
}

__device__ __forceinline__ short bf16bits(float f) {
    __hip_bfloat16 h = __float2bfloat16(f);
    return __builtin_bit_cast(short, h);
}

// Transpose x (B,F)->(F,B) and init out[b] with weighted group-bias terms.
__global__ void prep_kernel(const float* __restrict__ x,
                            const float* __restrict__ cbias,
                            const float* __restrict__ sbias,
                            float* __restrict__ xT, int do_transpose,
                            float* __restrict__ out) {
    int tid = blockIdx.x * blockDim.x + threadIdx.x;
    if (do_transpose && tid < kB * kF) {
        int f = tid >> 11, b = tid & (kB - 1);
        xT[f * kB + b] = x[b * kF + f];   // coalesced writes
    }
    if (tid < kB) {
        float acc = 0.f;
        #pragma unroll
        for (int g = 0; g < kC; ++g) acc += cbias[g] * kWCat;
        #pragma unroll
        for (int g = 0; g < kS; ++g) acc += sbias[g] * kWSub;
        out[tid] = acc;
    }
}

// Per-g raw weights held in registers (double-buffered across the g-loop).
struct GW { float w1[8], b1[8], w2[8], w3s, b2n, b3s; };

// One block per (f, 128-row chunk): 64*16 = 1024 blocks, 4 waves each.
// Each wave owns 2 MFMA row-tiles (32 batch rows) and loops all 15 groups.
__global__ __launch_bounds__(kThreads, 4) void nam_mfma(
    const float* __restrict__ xsrc, int trans,
    const float* __restrict__ cW1, const float* __restrict__ cB1,
    const float* __restrict__ cW2, const float* __restrict__ cB2,
    const float* __restrict__ cW3, const float* __restrict__ cB3,
    const float* __restrict__ sW1, const float* __restrict__ sB1,
    const float* __restrict__ sW2, const float* __restrict__ sB2,
    const float* __restrict__ sW3, const float* __restrict__ sB3,
    float* __restrict__ out) {
    const int f     = blockIdx.x % kF;
    const int chunk = blockIdx.x / kF;
    const int wave  = threadIdx.x >> 6;
    const int lane  = threadIdx.x & 63;
    const int n  = lane & 15;    // A-row / B-col / C-col index
    const int kg = lane >> 4;    // k-group (my convention: k = kg*8 + j)
    const int rowbase = chunk * kRowsPerBlock + wave * (kTPW * 16);

    // x values for my A-fragment rows (m = lane&15), one per tile.
    float xv[kTPW];
    if (trans) {
        #pragma unroll
        for (int t = 0; t < kTPW; ++t) xv[t] = xsrc[f * kB + rowbase + t * 16 + n];
    } else {
        #pragma unroll
        for (int t = 0; t < kTPW; ++t) xv[t] = xsrc[(rowbase + t * 16 + n) * kF + f];
    }

    GW buf[2];
    auto loadg = [&](int g, GW& w) {
        const float *W1, *B1, *W2, *B2, *W3, *B3; float wgt; int base;
        if (g < kC) { base = g * kF + f;
            W1 = cW1; B1 = cB1; W2 = cW2; B2 = cB2; W3 = cW3; B3 = cB3; wgt = kWCat;
        } else { base = (g - kC) * kF + f;
            W1 = sW1; B1 = sB1; W2 = sW2; B2 = sB2; W3 = sW3; B3 = sB3; wgt = kWSub;
        }
        const float* w1p = W1 + base * kH1 + kg * 8;
        const float* b1p = B1 + base * kH1 + kg * 8;
        #pragma unroll
        for (int j = 0; j < 8; ++j) w.w1[j] = w1p[j];
        #pragma unroll
        for (int j = 0; j < 8; ++j) w.b1[j] = b1p[j];
        const float* w2p = W2 + base * (kH1 * kH2) + (kg * 8) * kH2 + n;
        #pragma unroll
        for (int j = 0; j < 8; ++j) w.w2[j] = w2p[j * kH2];
        w.w3s = W3[base * kH2 + n] * wgt;
        w.b2n = B2[base * kH2 + n];
        w.b3s = B3[base] * wgt;
    };

    float out_part[kTPW][4];
    #pragma unroll
    for (int t = 0; t < kTPW; ++t)
        #pragma unroll
        for (int r = 0; r < 4; ++r) out_part[t][r] = 0.f;
    float bcon = 0.f;   // sum_g wgt_g * b3[g][f]  (per-b constant)

    loadg(0, buf[0]);
    #pragma unroll
    for (int g = 0; g < kG; ++g) {
        GW& w = buf[g & 1];
        if (g + 1 < kG) loadg(g + 1, buf[(g + 1) & 1]);   // prefetch next group

        short8_t bw;   // B-fragment: W2[k = kg*8+j][n], bf16
        #pragma unroll
        for (int j = 0; j < 8; ++j) bw[j] = bf16bits(w.w2[j]);
        bcon += w.b3s;

        #pragma unroll
        for (int t = 0; t < kTPW; ++t) {
            short8_t aw;   // A-fragment: h1[m = lane&15][k = kg*8+j], bf16
            #pragma unroll
            for (int j = 0; j < 8; ++j)
                aw[j] = bf16bits(fmaxf(fmaf(xv[t], w.w1[j], w.b1[j]), 0.f));
            f32x4 c = { w.b2n, w.b2n, w.b2n, w.b2n };
            c = __builtin_amdgcn_mfma_f32_16x16x32_bf16(aw, bw, c, 0, 0, 0);
            // C/D: col(n)=lane&15, row(m)=kg*4+r (m89-verified)
            #pragma unroll
            for (int r = 0; r < 4; ++r)
                out_part[t][r] = fmaf(fmaxf(c[r], 0.f), w.w3s, out_part[t][r]);
        }
    }

    // Reduce over the 16 h2-columns (lanes sharing kg), then one atomic per row.
    #pragma unroll
    for (int t = 0; t < kTPW; ++t)
        #pragma unroll
        for (int r = 0; r < 4; ++r) {
            float v = out_part[t][r] + ((n == 0) ? bcon : 0.f);
            v += __shfl_xor(v, 1);
            v += __shfl_xor(v, 2);
            v += __shfl_xor(v, 4);
            v += __shfl_xor(v, 8);
            if (n == 0) atomicAdd(&out[rowbase + t * 16 + kg * 4 + r], v);
        }
}

extern "C" void kernel_launch(void* const* d_in, const int* in_sizes, int n_in,
                              void* d_out, int out_size, void* d_ws, size_t ws_size,
                              hipStream_t stream) {
    const float* x     = (const float*)d_in[0];
    const float* cW1   = (const float*)d_in[1];
    const float* cB1   = (const float*)d_in[2];
    const float* cW2   = (const float*)d_in[3];
    const float* cB2   = (const float*)d_in[4];
    const float* cW3   = (const float*)d_in[5];
    const float* cB3   = (const float*)d_in[6];
    const float* cbias = (const float*)d_in[7];
    const float* sW1   = (const float*)d_in[8];
    const float* sB1   = (const float*)d_in[9];
    const float* sW2   = (const float*)d_in[10];
    const float* sB2   = (const float*)d_in[11];
    const float* sW3   = (const float*)d_in[12];
    const float* sB3   = (const float*)d_in[13];
    const float* sbias = (const float*)d_in[14];
    float* out = (float*)d_out;

    float* xT = (float*)d_ws;
    const int trans = (ws_size >= (size_t)(kB * kF) * sizeof(float)) ? 1 : 0;

    prep_kernel<<<(kB * kF + 255) / 256, 256, 0, stream>>>(x, cbias, sbias, xT, trans, out);
    const float* xin = trans ? (const float*)xT : x;
    nam_mfma<<<kF * kChunks, kThreads, 0, stream>>>(
        xin, trans, cW1, cB1, cW2, cB2, cW3, cB3,
        sW1, sB1, sW2, sB2, sW3, sB3, out);
}

// Round 4
// 33.999 us; speedup vs baseline: 1.2863x; 1.2863x over previous
//
#include <hip/hip_runtime.h>
#include <hip/hip_bf16.h>

typedef __attribute__((ext_vector_type(8))) short short8_t;
typedef __attribute__((ext_vector_type(4))) float f32x4;

namespace {
constexpr int kB = 2048;
constexpr int kF = 64;
constexpr int kC = 10;
constexpr int kS = 5;
constexpr int kG = kC + kS;          // 15 groups
constexpr int kH1 = 32;
constexpr int kH2 = 16;
constexpr float kWCat = 0.7f / kC;
constexpr float kWSub = 0.3f / kS;
constexpr int kThreads = 256;        // 4 waves
constexpr int kTPW = 2;              // 16-row MFMA tiles per wave
constexpr int kRowsPerBlock = 4 * kTPW * 16;   // 128
constexpr int kChunks = kB / kRowsPerBlock;    // 16

// ws layout (element offsets):
// wsA f32  [960][72] : per (g,f): [kg*16+0..7]=w1[kg*8+j], [kg*16+8..15]=b1[kg*8+j],
//                      [64]=wgt*b3, [65..71] pad.  (rec stride 288 B, 16B-aligned)
constexpr int kARec = 72;
constexpr size_t kAOffF = 0;                       // float offset
// wsB u16  [960][512]: per (g,f): lane l, j: bf16(W2[(l>>4)*8+j][l&15])
constexpr size_t kBOffU16 = 960 * kARec * 2;      // = 69120*2 u16 units after A
// wsC f32  [960][32] : per (g,f): n: {W3[n]*wgt, B2[n]} pairs
constexpr size_t kCOffF = (kBOffU16 + 960 * 512) / 2;  // float offset
// xT  f32  [64][2048]
constexpr size_t kXTOffF = kCOffF + 960 * 32;
constexpr size_t kWsNeedF = kXTOffF + (size_t)kF * kB;
}

__device__ __forceinline__ short bf16bits(float f) {
    __hip_bfloat16 h = __float2bfloat16(f);
    return __builtin_bit_cast(short, h);
}

// Pack all weights into MFMA-fragment order. One wave per (g,f). 960 blocks.
__global__ __launch_bounds__(64) void pack_kernel(
    const float* __restrict__ cW1, const float* __restrict__ cB1,
    const float* __restrict__ cW2, const float* __restrict__ cB2,
    const float* __restrict__ cW3, const float* __restrict__ cB3,
    const float* __restrict__ sW1, const float* __restrict__ sB1,
    const float* __restrict__ sW2, const float* __restrict__ sB2,
    const float* __restrict__ sW3, const float* __restrict__ sB3,
    float* __restrict__ wsA, unsigned short* __restrict__ wsB,
    float* __restrict__ wsC) {
    const int rec = blockIdx.x;          // g*64 + f
    const int g = rec >> 6, f = rec & (kF - 1);
    const int l = threadIdx.x;
    const float *W1, *B1, *W2, *B2, *W3, *B3; float wgt; int base;
    if (g < kC) {
        base = g * kF + f;
        W1 = cW1; B1 = cB1; W2 = cW2; B2 = cB2; W3 = cW3; B3 = cB3; wgt = kWCat;
    } else {
        base = (g - kC) * kF + f;
        W1 = sW1; B1 = sB1; W2 = sW2; B2 = sB2; W3 = sW3; B3 = sB3; wgt = kWSub;
    }
    // B-fragment: lane l -> W2[k=(l>>4)*8+j][n=l&15], j=0..7, bf16.
    const int n = l & 15, kg = l >> 4;
    const float* w2p = W2 + base * (kH1 * kH2) + (kg * 8) * kH2 + n;
    short8_t bw;
    #pragma unroll
    for (int j = 0; j < 8; ++j) bw[j] = bf16bits(w2p[j * kH2]);
    *(short8_t*)(wsB + (size_t)rec * 512 + l * 8) = bw;

    float* ra = wsA + (size_t)rec * kARec;
    if (l < kH1) {
        ra[(l >> 3) * 16 + (l & 7)]     = W1[base * kH1 + l];
        ra[(l >> 3) * 16 + 8 + (l & 7)] = B1[base * kH1 + l];
    }
    if (l < kH2) {
        float2 v;
        v.x = W3[base * kH2 + l] * wgt;
        v.y = B2[base * kH2 + l];
        *(float2*)(wsC + (size_t)rec * 32 + l * 2) = v;
    }
    if (l == 0) ra[64] = wgt * B3[base];
}

// Transpose x (B,F)->(F,B) and init out[b] with weighted group-bias terms.
__global__ void prep_kernel(const float* __restrict__ x,
                            const float* __restrict__ cbias,
                            const float* __restrict__ sbias,
                            float* __restrict__ xT,
                            float* __restrict__ out) {
    int tid = blockIdx.x * blockDim.x + threadIdx.x;
    if (tid < kB * kF) {
        int f = tid >> 11, b = tid & (kB - 1);
        xT[f * kB + b] = x[b * kF + f];   // coalesced writes
    }
    if (tid < kB) {
        float acc = 0.f;
        #pragma unroll
        for (int g = 0; g < kC; ++g) acc += cbias[g] * kWCat;
        #pragma unroll
        for (int g = 0; g < kS; ++g) acc += sbias[g] * kWSub;
        out[tid] = acc;
    }
}

// One block per (f, 128-row chunk): 64*16 = 1024 blocks, 4 waves each.
// Each wave owns 2 MFMA row-tiles (32 batch rows) and loops all 15 groups,
// reading packed weights with 7 wide loads per group. No LDS, no spills.
__global__ __launch_bounds__(kThreads, 4) void nam_mfma(
    const float* __restrict__ xT, const float* __restrict__ wsA,
    const unsigned short* __restrict__ wsB, const float* __restrict__ wsC,
    float* __restrict__ out) {
    const int f     = blockIdx.x & (kF - 1);
    const int chunk = blockIdx.x >> 6;
    const int wave  = threadIdx.x >> 6;
    const int lane  = threadIdx.x & 63;
    const int n  = lane & 15;
    const int kg = lane >> 4;
    const int rowbase = chunk * kRowsPerBlock + wave * (kTPW * 16);

    float xv[kTPW];
    #pragma unroll
    for (int t = 0; t < kTPW; ++t) xv[t] = xT[f * kB + rowbase + t * 16 + n];

    // Per-f base pointers; advance by constant record strides per group.
    const float* pA  = wsA + (size_t)f * kARec + kg * 16;
    const float* pA3 = wsA + (size_t)f * kARec + 64;
    const short8_t* pB = (const short8_t*)(wsB + (size_t)f * 512 + lane * 8);
    const float2* pC = (const float2*)(wsC + (size_t)f * 32 + n * 2);
    constexpr int strideA = kF * kARec;             // floats per g step
    constexpr int strideB = kF * 512 / 8;           // short8 units per g step
    constexpr int strideC = kF * 32 / 2;            // float2 units per g step

    float out_part[kTPW][4];
    #pragma unroll
    for (int t = 0; t < kTPW; ++t)
        #pragma unroll
        for (int r = 0; r < 4; ++r) out_part[t][r] = 0.f;
    float bcon = 0.f;   // sum_g wgt_g * b3[g][f]

    #pragma unroll 3
    for (int g = 0; g < kG; ++g) {
        const f32x4 w1a = *(const f32x4*)(pA + 0);   // w1 j=0..3
        const f32x4 w1b = *(const f32x4*)(pA + 4);   // w1 j=4..7
        const f32x4 b1a = *(const f32x4*)(pA + 8);   // b1 j=0..3
        const f32x4 b1b = *(const f32x4*)(pA + 12);  // b1 j=4..7
        const float b3s = *pA3;
        const short8_t bw = *pB;
        const float2 wc = *pC;                       // {w3*wgt, b2}
        bcon += b3s;

        #pragma unroll
        for (int t = 0; t < kTPW; ++t) {
            short8_t aw;
            aw[0] = bf16bits(fmaxf(fmaf(xv[t], w1a.x, b1a.x), 0.f));
            aw[1] = bf16bits(fmaxf(fmaf(xv[t], w1a.y, b1a.y), 0.f));
            aw[2] = bf16bits(fmaxf(fmaf(xv[t], w1a.z, b1a.z), 0.f));
            aw[3] = bf16bits(fmaxf(fmaf(xv[t], w1a.w, b1a.w), 0.f));
            aw[4] = bf16bits(fmaxf(fmaf(xv[t], w1b.x, b1b.x), 0.f));
            aw[5] = bf16bits(fmaxf(fmaf(xv[t], w1b.y, b1b.y), 0.f));
            aw[6] = bf16bits(fmaxf(fmaf(xv[t], w1b.z, b1b.z), 0.f));
            aw[7] = bf16bits(fmaxf(fmaf(xv[t], w1b.w, b1b.w), 0.f));
            f32x4 c = { wc.y, wc.y, wc.y, wc.y };
            c = __builtin_amdgcn_mfma_f32_16x16x32_bf16(aw, bw, c, 0, 0, 0);
            // C/D: col=lane&15, row=kg*4+r (verified in R3)
            #pragma unroll
            for (int r = 0; r < 4; ++r)
                out_part[t][r] = fmaf(fmaxf(c[r], 0.f), wc.x, out_part[t][r]);
        }
        pA += strideA; pA3 += strideA; pB += strideB; pC += strideC;
    }

    // Reduce over the 16 h2-columns (lanes with same kg), one atomic per row.
    #pragma unroll
    for (int t = 0; t < kTPW; ++t)
        #pragma unroll
        for (int r = 0; r < 4; ++r) {
            float v = out_part[t][r] + ((n == 0) ? bcon : 0.f);
            v += __shfl_xor(v, 1);
            v += __shfl_xor(v, 2);
            v += __shfl_xor(v, 4);
            v += __shfl_xor(v, 8);
            if (n == 0) atomicAdd(&out[rowbase + t * 16 + kg * 4 + r], v);
        }
}

extern "C" void kernel_launch(void* const* d_in, const int* in_sizes, int n_in,
                              void* d_out, int out_size, void* d_ws, size_t ws_size,
                              hipStream_t stream) {
    const float* x     = (const float*)d_in[0];
    const float* cW1   = (const float*)d_in[1];
    const float* cB1   = (const float*)d_in[2];
    const float* cW2   = (const float*)d_in[3];
    const float* cB2   = (const float*)d_in[4];
    const float* cW3   = (const float*)d_in[5];
    const float* cB3   = (const float*)d_in[6];
    const float* cbias = (const float*)d_in[7];
    const float* sW1   = (const float*)d_in[8];
    const float* sB1   = (const float*)d_in[9];
    const float* sW2   = (const float*)d_in[10];
    const float* sB2   = (const float*)d_in[11];
    const float* sW3   = (const float*)d_in[12];
    const float* sB3   = (const float*)d_in[13];
    const float* sbias = (const float*)d_in[14];
    float* out = (float*)d_out;

    float* wsF = (float*)d_ws;
    float* wsA = wsF + kAOffF;
    unsigned short* wsB = (unsigned short*)d_ws + kBOffU16;
    float* wsC = wsF + kCOffF;
    float* xT  = wsF + kXTOffF;
    (void)ws_size; (void)kWsNeedF;   // ws_size (≈268 MB observed) ≫ 1.9 MB needed

    pack_kernel<<<kG * kF, 64, 0, stream>>>(cW1, cB1, cW2, cB2, cW3, cB3,
                                            sW1, sB1, sW2, sB2, sW3, sB3,
                                            wsA, wsB, wsC);
    prep_kernel<<<(kB * kF + 255) / 256, 256, 0, stream>>>(x, cbias, sbias, xT, out);
    nam_mfma<<<kF * kChunks, kThreads, 0, stream>>>(xT, wsA, wsB, wsC, out);
}